// Round 5
// baseline (2034.793 us; speedup 1.0000x reference)
//
#include <hip/hip_runtime.h>
#include <hip/hip_bf16.h>

#define TT 2048
#define BB 32
#define DD 256
#define HH 256
#define GG 768   // 3*H

typedef _Float16 half2_t __attribute__((ext_vector_type(2)));

__device__ inline float fdot2(unsigned int w, unsigned int h, float acc) {
#if __has_builtin(__builtin_amdgcn_fdot2)
    return __builtin_amdgcn_fdot2(__builtin_bit_cast(half2_t, w),
                                  __builtin_bit_cast(half2_t, h), acc, false);
#else
    half2_t a = __builtin_bit_cast(half2_t, w);
    half2_t b = __builtin_bit_cast(half2_t, h);
    return acc + (float)a.x * (float)b.x + (float)a.y * (float)b.y;
#endif
}

// ---------- helpers for fp32/bf16 workspace storage of gi ----------
__device__ inline void store4(float* p, float a, float b, float c, float d) {
    *(float4*)p = make_float4(a, b, c, d);
}
__device__ inline void store4(__hip_bfloat16* p, float a, float b, float c, float d) {
    p[0] = __float2bfloat16(a);
    p[1] = __float2bfloat16(b);
    p[2] = __float2bfloat16(c);
    p[3] = __float2bfloat16(d);
}
__device__ inline float ldgi(const float* p) { return *p; }
__device__ inline float ldgi(const __hip_bfloat16* p) { return __bfloat162float(*p); }

// ---------- pack w_hh [768][256] f32 into the 512-thread ownership layout ---
// Region A (u32 idx 0..65535):  idx=(q4*512+t)*4+i -> col=t,        k=8*q4+2i
// Region B (u32 idx 65536..):   idx2=(p4*512+t)*4+i -> col=512+(t>>1),
//                               k=(t&1)*128 + 8*p4 + 2i
__global__ __launch_bounds__(256)
void pack_w(const float* __restrict__ w, unsigned int* __restrict__ wf) {
    int i = blockIdx.x * 256 + threadIdx.x;  // 0 .. 98303
    int col, k;
    if (i < 65536) {
        int comp = i & 3, t = (i >> 2) & 511, q4 = i >> 11;
        col = t;
        k = 8 * q4 + 2 * comp;
    } else {
        int i2 = i - 65536;
        int comp = i2 & 3, t = (i2 >> 2) & 511, p4 = i2 >> 11;
        col = 512 + (t >> 1);
        k = (t & 1) * 128 + 8 * p4 + 2 * comp;
    }
    float a = w[(size_t)col * DD + k];
    float b = w[(size_t)col * DD + k + 1];
    half2_t h = {(_Float16)a, (_Float16)b};
    wf[i] = __builtin_bit_cast(unsigned int, h);
}

// ---------- gi = seq @ w_ih^T + b_ih ; M=65536, N=768, K=256 ----------
template <typename GiT>
__global__ __launch_bounds__(256)
void gemm_gi(const float* __restrict__ A,     // [M][256]
             const float* __restrict__ W,     // [768][256]
             const float* __restrict__ bias,  // [768]
             GiT* __restrict__ C)              // [M][768]
{
    __shared__ float As[32][68];
    __shared__ float Ws[32][68];
    const int tid = threadIdx.x;
    const int bm = blockIdx.y * 64;
    const int bn = blockIdx.x * 64;
    const int tm = (tid & 15) * 4;
    const int tn = (tid >> 4) * 4;
    const int r  = tid >> 3;
    const int c4 = (tid & 7) * 4;

    float acc[4][4] = {};

    for (int k0 = 0; k0 < 256; k0 += 32) {
#pragma unroll
        for (int rr = 0; rr < 64; rr += 32) {
            float4 a = *(const float4*)&A[(size_t)(bm + r + rr) * 256 + k0 + c4];
            As[c4 + 0][r + rr] = a.x;
            As[c4 + 1][r + rr] = a.y;
            As[c4 + 2][r + rr] = a.z;
            As[c4 + 3][r + rr] = a.w;
            float4 w = *(const float4*)&W[(size_t)(bn + r + rr) * 256 + k0 + c4];
            Ws[c4 + 0][r + rr] = w.x;
            Ws[c4 + 1][r + rr] = w.y;
            Ws[c4 + 2][r + rr] = w.z;
            Ws[c4 + 3][r + rr] = w.w;
        }
        __syncthreads();
#pragma unroll
        for (int kk = 0; kk < 32; ++kk) {
            float4 a = *(const float4*)&As[kk][tm];
            float4 w = *(const float4*)&Ws[kk][tn];
            float av[4] = {a.x, a.y, a.z, a.w};
            float wv[4] = {w.x, w.y, w.z, w.w};
#pragma unroll
            for (int i = 0; i < 4; ++i)
#pragma unroll
                for (int j = 0; j < 4; ++j)
                    acc[i][j] += av[i] * wv[j];
        }
        __syncthreads();
    }
#pragma unroll
    for (int i = 0; i < 4; ++i) {
        GiT* cp = C + (size_t)(bm + tm + i) * GG + bn + tn;
        store4(cp, acc[i][0] + bias[bn + tn + 0],
                   acc[i][1] + bias[bn + tn + 1],
                   acc[i][2] + bias[bn + tn + 2],
                   acc[i][3] + bias[bn + tn + 3]);
    }
}

// ---------- sequential scan: 1 wg (512 thr) per batch row, mask-skip -------
// 2 waves/SIMD -> 256-VGPR budget; 192 weight u32/thread stays resident.
// Thread t: full col t (cols 0..511) + half-K of col 512+(t>>1).
template <typename GiT>
__global__ __launch_bounds__(512, 2)
void gru_scan(const GiT* __restrict__ gi,          // [T*B][768]
              const int* __restrict__ mask,         // [T*B]
              const float* __restrict__ h0,         // [B][256]
              const unsigned int* __restrict__ wpk, // packed, see pack_w
              const float* __restrict__ b_hh,       // [768]
              float* __restrict__ out,              // [T*B][256]
              float* __restrict__ hfin)             // [B][256]
{
    const int b = blockIdx.x;
    const int t = threadIdx.x;  // 0..511
    __shared__ __align__(16) _Float16 hhalf[HH];  // f16 state for the GEMV
    __shared__ float gh_lds[GG];
    __shared__ int mlds[TT];

    // --- one-time: weights into 192 VGPRs (uint4 loads, coalesced) ---
    uint4 wA[32];
    uint4 wB[16];
    {
        const uint4* wp = (const uint4*)wpk;
#pragma unroll
        for (int q4 = 0; q4 < 32; ++q4)
            wA[q4] = wp[q4 * 512 + t];
        const uint4* wpB = wp + 32 * 512;
#pragma unroll
        for (int p4 = 0; p4 < 16; ++p4)
            wB[p4] = wpB[p4 * 512 + t];
    }

    for (int i = t; i < TT; i += 512)
        mlds[i] = mask[i * BB + b];

    float h_r = 0.f, bh0 = 0.f, bh1 = 0.f, bh2 = 0.f;
    if (t < HH) {
        h_r = h0[b * HH + t];
        hhalf[t] = (_Float16)h_r;
        bh0 = b_hh[t];
        bh1 = b_hh[t + HH];
        bh2 = b_hh[t + 2 * HH];
    }
    __syncthreads();

    const uint4* hu4 = (const uint4*)hhalf;                      // 32 x uint4
    const uint4* hB  = (const uint4*)(hhalf + (t & 1) * 128);    // 16 x uint4

    for (int ts = 0; ts < TT; ++ts) {
        if (mlds[ts]) {
            // gi loads issued now, consumed in the gate phase (~1000+ cyc
            // later; GEMV + barrier cover the HBM/L3 latency)
            float ir = 0.f, iz = 0.f, inn = 0.f;
            if (t < HH) {
                const GiT* gtb = gi + ((size_t)ts * BB + b) * GG;
                ir  = ldgi(gtb + t);
                iz  = ldgi(gtb + t + HH);
                inn = ldgi(gtb + t + 2 * HH);
            }

            // --- GEMV, part A: own column t, full K ---
            float a0 = 0.f, a1 = 0.f, a2 = 0.f, a3 = 0.f;
#pragma unroll
            for (int q4 = 0; q4 < 32; ++q4) {
                uint4 hv = hu4[q4];  // wave-uniform -> LDS broadcast
                a0 = fdot2(wA[q4].x, hv.x, a0);
                a1 = fdot2(wA[q4].y, hv.y, a1);
                a2 = fdot2(wA[q4].z, hv.z, a2);
                a3 = fdot2(wA[q4].w, hv.w, a3);
            }
            // --- GEMV, part B: half-K of column 512+(t>>1) ---
            float c0 = 0.f, c1 = 0.f, c2 = 0.f, c3 = 0.f;
#pragma unroll
            for (int p4 = 0; p4 < 16; ++p4) {
                uint4 hv = hB[p4];  // 2 distinct addrs/wave -> conflict-free
                c0 = fdot2(wB[p4].x, hv.x, c0);
                c1 = fdot2(wB[p4].y, hv.y, c1);
                c2 = fdot2(wB[p4].z, hv.z, c2);
                c3 = fdot2(wB[p4].w, hv.w, c3);
            }
            float accB = (c0 + c1) + (c2 + c3);
            float accBo = __shfl_xor(accB, 1);  // partner half-K (same wave)
            gh_lds[t] = (a0 + a1) + (a2 + a3);
            if (!(t & 1))
                gh_lds[512 + (t >> 1)] = accB + accBo;
            __syncthreads();  // gh visible; hhalf reads done

            if (t < HH) {
                float hr = gh_lds[t] + bh0;
                float hz = gh_lds[t + HH] + bh1;
                float hn = gh_lds[t + 2 * HH] + bh2;
                float r = 1.f / (1.f + __expf(-(ir + hr)));
                float z = 1.f / (1.f + __expf(-(iz + hz)));
                float e = __expf(2.f * (inn + r * hn));
                float n = 1.f - 2.f / (e + 1.f);
                float ht = (1.f - z) * n + z * h_r;
                out[((size_t)ts * BB + b) * HH + t] = ht;
                h_r = ht;
                hhalf[t] = (_Float16)ht;
            }
            __syncthreads();  // h update visible before next GEMV
        } else {
            // masked: h unchanged, output row exactly zero; no barriers
            // (branch is block-uniform)
            if (t < HH)
                out[((size_t)ts * BB + b) * HH + t] = 0.f;
        }
    }
    if (t < HH) hfin[b * HH + t] = h_r;
}

extern "C" void kernel_launch(void* const* d_in, const int* in_sizes, int n_in,
                              void* d_out, int out_size, void* d_ws, size_t ws_size,
                              hipStream_t stream) {
    const float* seq  = (const float*)d_in[0];
    const int*   mask = (const int*)  d_in[1];
    const float* h0   = (const float*)d_in[2];
    const float* w_ih = (const float*)d_in[3];
    const float* w_hh = (const float*)d_in[4];
    const float* b_ih = (const float*)d_in[5];
    const float* b_hh = (const float*)d_in[6];

    float* out  = (float*)d_out;
    float* hfin = out + (size_t)TT * BB * HH;

    // workspace layout: [wpk: 128*768 u32][gi: T*B*768 f32 (or bf16 fallback)]
    const size_t wpk_elems = (size_t)128 * GG;
    unsigned int* wpk = (unsigned int*)d_ws;
    const size_t gi_elems = (size_t)TT * BB * GG;
    const size_t need_f32 = wpk_elems * 4 + gi_elems * 4;

    pack_w<<<(128 * GG) / 256, 256, 0, stream>>>(w_hh, wpk);

    dim3 ggrid(GG / 64, (TT * BB) / 64);
    if (ws_size >= need_f32) {
        float* gip = (float*)d_ws + wpk_elems;
        gemm_gi<float><<<ggrid, 256, 0, stream>>>(seq, w_ih, b_ih, gip);
        gru_scan<float><<<BB, 512, 0, stream>>>(gip, mask, h0, wpk, b_hh, out, hfin);
    } else {
        __hip_bfloat16* gip = (__hip_bfloat16*)((float*)d_ws + wpk_elems);
        gemm_gi<__hip_bfloat16><<<ggrid, 256, 0, stream>>>(seq, w_ih, b_ih, gip);
        gru_scan<__hip_bfloat16><<<BB, 512, 0, stream>>>(gip, mask, h0, wpk, b_hh, out, hfin);
    }
}